// Round 9
// baseline (101.282 us; speedup 1.0000x reference)
//
#include <hip/hip_runtime.h>
#include <hip/hip_bf16.h>

#define NN  50000
#define DD  256
#define KNB 16
#define BM  64
#define NSL 8      // column slices (one per XCD)
#define SLW 32     // slice width in columns (64B bf16 rows -> line-pure slices)
#define NKT 8      // 256 / 32
#define NGRP ((NN + 63) / 64)   // 782 node-groups of 64

typedef __attribute__((ext_vector_type(8))) short bf16x8;
typedef __attribute__((ext_vector_type(4))) float f32x4;
typedef __attribute__((ext_vector_type(4))) int   i32x4;

static __device__ __forceinline__ float bf2f(unsigned int u16) {
    union { unsigned int i; float f; } c; c.i = u16 << 16; return c.f;
}
static __device__ __forceinline__ float bf2f_hi(unsigned int u) {
    union { unsigned int i; float f; } c; c.i = u & 0xffff0000u; return c.f;
}
static __device__ __forceinline__ short f2bf(float f) {
    union { float f; unsigned int i; } c; c.f = f;
    unsigned int r = c.i + 0x7FFFu + ((c.i >> 16) & 1u);   // RNE
    return (short)(r >> 16);
}
static __device__ __forceinline__ bf16x8 pack8(float4 a, float4 b) {
    union { __hip_bfloat162 h[4]; bf16x8 v; } u;
    u.h[0] = __float22bfloat162_rn(make_float2(a.x, a.y));
    u.h[1] = __float22bfloat162_rn(make_float2(a.z, a.w));
    u.h[2] = __float22bfloat162_rn(make_float2(b.x, b.y));
    u.h[3] = __float22bfloat162_rn(make_float2(b.z, b.w));
    return u.v;
}

#define GLOAD_LDS16(g, l) \
    __builtin_amdgcn_global_load_lds((const __attribute__((address_space(1))) unsigned int*)(g), \
                                     (__attribute__((address_space(3))) unsigned int*)(l), 16, 0, 0)

// ---------------------------------------------------------------------------
// Kernel 0: W (f32, row-major 256x256) -> bf16 fragment-tiled Wbf.
// slot s = ((kt*16 + nb)*4 + kb)*16 + j  holds 8 bf16:
//   Wbf[s*8 + e] = W[nb*16 + j][kt*32 + kb*8 + e]
// For fixed kt, nb-range [cg*8, cg*8+8) is a contiguous 8 KB half-slice.
// ---------------------------------------------------------------------------
__global__ void convert_w(const float* __restrict__ W, unsigned short* __restrict__ Wbf)
{
    int s = blockIdx.x * blockDim.x + threadIdx.x;   // 8192 slots
    if (s >= 8192) return;
    int j  = s & 15;
    int kb = (s >> 4) & 3;
    int nb = (s >> 6) & 15;
    int kt = s >> 10;
    const float4* p = (const float4*)(W + (nb * 16 + j) * DD + kt * 32 + kb * 8);
    *(bf16x8*)&Wbf[(size_t)s * 8] = pack8(p[0], p[1]);
}

// ---------------------------------------------------------------------------
// Kernel 1: x = relu(feats @ W^T + b) -> bf16 in SLICED layout:
//   xs[(col>>5)*NN*32 + row*32 + (col&31)]
// Block = 64 rows x 128 cols, 256 thr / 4 waves; wave = 64r x 32c (m4 x n2).
// The block's 128-col W panel (64 KB, pre-tiled) is staged in LDS ONCE via
// global_load_lds; ONE barrier; then the 8-step K-loop is BARRIER-FREE:
// A fragments stream per-lane from global (4 waves x 8 kt reuse each A line
// via L1), W frags via ds_read_b128. LDS 64 KB -> 2 blocks/CU.
// ---------------------------------------------------------------------------
__global__ __launch_bounds__(256, 2) void gemm_relu(
    const float* __restrict__ feats, const unsigned short* __restrict__ Wbf,
    const float* __restrict__ bias, unsigned short* __restrict__ xs)
{
    __shared__ short Wt[32768];   // 64 KB  [kt8][nbL8][kb4][j16][e8]

    const int tid  = threadIdx.x;
    const int lane = tid & 63;
    const int wc   = tid >> 6;         // wave owns cols cg*128 + wc*32 ..+32
    const int l15  = lane & 15;
    const int lg   = lane >> 4;
    const int rg   = blockIdx.x >> 1;  // row-group
    const int cg   = blockIdx.x & 1;   // col-half
    const int blockRow = rg * BM;

    // ---- stage the 64 KB W half-panel (16 x 16B per thread), one barrier ----
    {
        const char* wsrc = (const char*)Wbf + cg * 8192 + tid * 16;
        char* wdst = (char*)Wt + tid * 16;
        #pragma unroll
        for (int p = 0; p < 16; ++p)
            GLOAD_LDS16(wsrc + (p >> 1) * 16384 + (p & 1) * 4096,
                        wdst + p * 4096);
    }

    // ---- A row pointers (clamped; garbage rows masked at store) ----
    const float* aptr[4];
    #pragma unroll
    for (int m = 0; m < 4; ++m) {
        int r = blockRow + m * 16 + l15;
        if (r > NN - 1) r = NN - 1;
        aptr[m] = feats + (size_t)r * DD + lg * 8;
    }

    float bv[2];
    #pragma unroll
    for (int n = 0; n < 2; ++n) bv[n] = bias[cg * 128 + wc * 32 + n * 16 + l15];

    f32x4 acc[4][2];
    #pragma unroll
    for (int m = 0; m < 4; ++m)
        #pragma unroll
        for (int n = 0; n < 2; ++n) acc[m][n] = (f32x4)0.0f;

    __syncthreads();   // W panel ready; no further barriers

    #pragma unroll
    for (int kt = 0; kt < NKT; ++kt) {
        bf16x8 afr[4], bfr[2];
        #pragma unroll
        for (int m = 0; m < 4; ++m) {
            float4 lo = *(const float4*)(aptr[m] + kt * 32);
            float4 hi = *(const float4*)(aptr[m] + kt * 32 + 4);
            afr[m] = pack8(lo, hi);
        }
        #pragma unroll
        for (int n = 0; n < 2; ++n)
            bfr[n] = *(const bf16x8*)&Wt[(((kt * 8 + wc * 2 + n) * 4 + lg) * 16 + l15) * 8];

        #pragma unroll
        for (int m = 0; m < 4; ++m)
            #pragma unroll
            for (int n = 0; n < 2; ++n)
                acc[m][n] = __builtin_amdgcn_mfma_f32_16x16x32_bf16(
                    afr[m], bfr[n], acc[m][n], 0, 0, 0);
    }

    // ---- epilogue: bias + relu -> sliced bf16 store ----
    const int sl = cg * 4 + wc;                    // both n sub-cols same slice
    unsigned short* xbase = xs + (size_t)sl * NN * SLW;
    #pragma unroll
    for (int n = 0; n < 2; ++n) {
        const int c = n * 16 + l15;
        #pragma unroll
        for (int m = 0; m < 4; ++m) {
            int rbase = blockRow + m * 16 + (lg << 2);
            f32x4 a = acc[m][n];
            #pragma unroll
            for (int r = 0; r < 4; ++r) {
                int row = rbase + r;
                if (row < NN) {
                    float vv = fmaxf(a[r] + bv[n], 0.0f);
                    xbase[(size_t)row * SLW + c] = (unsigned short)f2bf(vv);
                }
            }
        }
    }
}

// ---------------------------------------------------------------------------
// Kernel 2: out[i, s*32..s*32+32) = mean_k xs[s][edge[i,k], :].
// Persistent grid 2048 = 256 CU x 8; slice s = blockIdx.x & 7 pinned per XCD
// (3.2 MB slice L2-resident). Wave = 16 nodes; lane = node(g) x quad(q).
// Coalesced cached int4 edge load + static __shfl. Gather loads BATCHED
// 8-deep into registers before accumulating (keeps ~8 L2 loads in flight
// per wave vs ~3 when fused -- r8 was L2-latency-bound at VGPR=40).
// NT only on write-once out stores.
// ---------------------------------------------------------------------------
__global__ __launch_bounds__(256) void gather_mean(
    const int* __restrict__ edge, const unsigned short* __restrict__ xs,
    float* __restrict__ out)
{
    const int s    = blockIdx.x & 7;
    const int lane = threadIdx.x & 63;
    const int w    = threadIdx.x >> 6;
    const int g    = lane >> 2, q = lane & 3;
    const unsigned short* xsl = xs + (size_t)s * NN * SLW;
    const unsigned qo = q * 8;

    for (int grp = blockIdx.x >> 3; grp < NGRP; grp += 256) {
        const int iw0 = grp * 64 + w * 16;
        const int i   = iw0 + g;

        int eoff = iw0 * KNB + lane * 4;
        if (eoff > NN * KNB - 4) eoff = NN * KNB - 4;
        i32x4 e4 = *(const i32x4*)(edge + eoff);
        int e[4] = { e4[0], e4[1], e4[2], e4[3] };

        float a[8];
        #pragma unroll
        for (int j = 0; j < 8; ++j) a[j] = 0.0f;

        #pragma unroll
        for (int half = 0; half < 2; ++half) {
            bf16x8 vbuf[8];
            #pragma unroll
            for (int kk = 0; kk < 8; ++kk) {            // issue 8 loads
                int k = half * 8 + kk;
                int src = (lane & 60) | (k >> 2);
                unsigned n = (unsigned)__shfl(e[k & 3], src, 64);
                vbuf[kk] = *(const bf16x8*)(xsl + n * SLW + qo);
            }
            #pragma unroll
            for (int kk = 0; kk < 8; ++kk) {            // then consume
                const unsigned int* vu = (const unsigned int*)&vbuf[kk];
                #pragma unroll
                for (int j = 0; j < 4; ++j) {
                    a[2 * j]     += bf2f(vu[j] & 0xffffu);
                    a[2 * j + 1] += bf2f_hi(vu[j]);
                }
            }
        }

        if (i < NN) {
            f32x4 o0 = { a[0] * 0.0625f, a[1] * 0.0625f, a[2] * 0.0625f, a[3] * 0.0625f };
            f32x4 o1 = { a[4] * 0.0625f, a[5] * 0.0625f, a[6] * 0.0625f, a[7] * 0.0625f };
            float* op = out + (size_t)i * DD + s * SLW + q * 8;
            __builtin_nontemporal_store(o0, (f32x4*)op);
            __builtin_nontemporal_store(o1, (f32x4*)(op + 4));
        }
    }
}

extern "C" void kernel_launch(void* const* d_in, const int* in_sizes, int n_in,
                              void* d_out, int out_size, void* d_ws, size_t ws_size,
                              hipStream_t stream) {
    // inputs: 0:idx 1:feats 2:edge_dict 3:sadj 4:epoch 5:W 6:b
    const float* feats = (const float*)d_in[1];
    const int*   edge  = (const int*)d_in[2];
    const float* W     = (const float*)d_in[5];
    const float* b     = (const float*)d_in[6];
    float* out = (float*)d_out;

    unsigned short* xs  = (unsigned short*)d_ws;                            // 25.6 MB sliced
    unsigned short* Wbf = (unsigned short*)((char*)d_ws + (size_t)NN * DD * 2); // +128 KB

    convert_w<<<dim3(32), dim3(256), 0, stream>>>(W, Wbf);
    gemm_relu<<<dim3(NGRP * 2), dim3(256), 0, stream>>>(feats, Wbf, b, xs);
    gather_mean<<<dim3(2048), dim3(256), 0, stream>>>(edge, xs, out);
}

// Round 10
// 68.551 us; speedup vs baseline: 1.4775x; 1.4775x over previous
//
#include <hip/hip_runtime.h>
#include <hip/hip_bf16.h>

#define NN  50000
#define DD  256
#define KNB 16
#define BM  32
#define NSL 8      // column slices (one per XCD)
#define SLW 32     // slice width in columns (64B bf16 rows -> line-pure slices)
#define NKT 8      // 256 / 32
#define NGRP ((NN + 63) / 64)    // 782 node-groups of 64 (gather)
#define NB32 ((NN + 31) / 32)    // 1563 row-blocks of 32 (gemm)

typedef __attribute__((ext_vector_type(8))) short bf16x8;
typedef __attribute__((ext_vector_type(4))) float f32x4;
typedef __attribute__((ext_vector_type(4))) int   i32x4;

static __device__ __forceinline__ float bf2f(unsigned int u16) {
    union { unsigned int i; float f; } c; c.i = u16 << 16; return c.f;
}
static __device__ __forceinline__ float bf2f_hi(unsigned int u) {
    union { unsigned int i; float f; } c; c.i = u & 0xffff0000u; return c.f;
}
static __device__ __forceinline__ short f2bf(float f) {
    union { float f; unsigned int i; } c; c.f = f;
    unsigned int r = c.i + 0x7FFFu + ((c.i >> 16) & 1u);   // RNE
    return (short)(r >> 16);
}
static __device__ __forceinline__ bf16x8 pack8(float4 a, float4 b) {
    union { __hip_bfloat162 h[4]; bf16x8 v; } u;
    u.h[0] = __float22bfloat162_rn(make_float2(a.x, a.y));
    u.h[1] = __float22bfloat162_rn(make_float2(a.z, a.w));
    u.h[2] = __float22bfloat162_rn(make_float2(b.x, b.y));
    u.h[3] = __float22bfloat162_rn(make_float2(b.z, b.w));
    return u.v;
}

#define GLOAD_LDS16(g, l) \
    __builtin_amdgcn_global_load_lds((const __attribute__((address_space(1))) unsigned int*)(g), \
                                     (__attribute__((address_space(3))) unsigned int*)(l), 16, 0, 0)

// ---------------------------------------------------------------------------
// Kernel 0: W (f32, row-major 256x256) -> bf16 fragment-tiled Wbf.
// slot s = ((kt*16 + nb)*4 + kb)*16 + j  holds 8 bf16:
//   Wbf[s*8 + e] = W[nb*16 + j][kt*32 + kb*8 + e]
// Per-kt tile = contiguous 16 KB, staged by global_load_lds in the GEMM.
// ---------------------------------------------------------------------------
__global__ void convert_w(const float* __restrict__ W, unsigned short* __restrict__ Wbf)
{
    int s = blockIdx.x * blockDim.x + threadIdx.x;   // 8192 slots
    if (s >= 8192) return;
    int j  = s & 15;
    int kb = (s >> 4) & 3;
    int nb = (s >> 6) & 15;
    int kt = s >> 10;
    const float4* p = (const float4*)(W + (nb * 16 + j) * DD + kt * 32 + kb * 8);
    *(bf16x8*)&Wbf[(size_t)s * 8] = pack8(p[0], p[1]);
}

// ---------------------------------------------------------------------------
// Kernel 1: x = relu(feats @ W^T + b) -> bf16 in SLICED layout:
//   xs[(col>>5)*NN*32 + row*32 + (col&31)]
// BM=32, 256 thr / 4 waves; wave wc owns cols [wc*64, wc*64+64) (m2 x n4).
// A (32x256, 16 KB) staged ONCE in prologue; W double-buffered 2x16 KB via
// global_load_lds from L2-resident pre-tiled Wbf, one barrier per K-step.
// LDS = 48 KB -> 3 blocks/CU = 12 waves/CU (r5's 64KB/8-wave was the limit).
// ---------------------------------------------------------------------------
__global__ __launch_bounds__(256, 3) void gemm_relu(
    const float* __restrict__ feats, const unsigned short* __restrict__ Wbf,
    const float* __restrict__ bias, unsigned short* __restrict__ xs)
{
    __shared__ short At[8192];         // 16 KB  [kt8][m2][kq4][i16][e8]
    __shared__ short Wt[2][8192];      // 32 KB  [nb16][kq4][j16][e8] per buf

    const int tid  = threadIdx.x;
    const int lane = tid & 63;
    const int wc   = tid >> 6;
    const int l15  = lane & 15;
    const int lg   = lane >> 4;
    const int blockRow = blockIdx.x * BM;

    auto wstage = [&](int kt, int buf) {
        const char* src = (const char*)Wbf + kt * 16384 + tid * 16;
        char* dst = (char*)&Wt[buf][0] + tid * 16;
        #pragma unroll
        for (int c = 0; c < 4; ++c)
            GLOAD_LDS16(src + c * 4096, dst + c * 4096);
    };

    // ---- stage W(kt=0), then the whole 32x256 A tile (once) ----
    wstage(0, 0);
    {
        const int r = tid >> 3, q = tid & 7;      // row 0..31, kt-chunk 0..7
        int row = blockRow + r; if (row > NN - 1) row = NN - 1;  // clamp; masked at store
        const float* base = feats + (size_t)row * DD + q * 32;
        const int m = r >> 4, i15 = r & 15;
        #pragma unroll
        for (int kq = 0; kq < 4; ++kq) {
            float4 lo = *(const float4*)(base + kq * 8);
            float4 hi = *(const float4*)(base + kq * 8 + 4);
            int slot = (((q * 2 + m) * 4 + kq) * 16 + i15) * 8;
            *(bf16x8*)&At[slot] = pack8(lo, hi);
        }
    }

    float bv[4];
    #pragma unroll
    for (int n = 0; n < 4; ++n) bv[n] = bias[wc * 64 + n * 16 + l15];

    f32x4 acc[2][4];
    #pragma unroll
    for (int m = 0; m < 2; ++m)
        #pragma unroll
        for (int n = 0; n < 4; ++n) acc[m][n] = (f32x4)0.0f;

    __syncthreads();   // A + W(0) ready

    #pragma unroll
    for (int kt = 0; kt < NKT; ++kt) {
        const int cur = kt & 1;
        if (kt + 1 < NKT) wstage(kt + 1, cur ^ 1);   // prefetch next W tile

        bf16x8 afr[2], bfr[4];
        #pragma unroll
        for (int m = 0; m < 2; ++m)
            afr[m] = *(const bf16x8*)&At[(((kt * 2 + m) * 4 + lg) * 16 + l15) * 8];
        #pragma unroll
        for (int n = 0; n < 4; ++n)
            bfr[n] = *(const bf16x8*)&Wt[cur][(((wc * 4 + n) * 4 + lg) * 16 + l15) * 8];

        #pragma unroll
        for (int m = 0; m < 2; ++m)
            #pragma unroll
            for (int n = 0; n < 4; ++n)
                acc[m][n] = __builtin_amdgcn_mfma_f32_16x16x32_bf16(
                    afr[m], bfr[n], acc[m][n], 0, 0, 0);

        __syncthreads();   // drains wstage(kt+1); Wt[cur^1] ready for next step
    }

    // ---- epilogue: bias + relu -> sliced bf16 store ----
    #pragma unroll
    for (int n = 0; n < 4; ++n) {
        const int sl = wc * 2 + (n >> 1);
        const int c  = (n & 1) * 16 + l15;
        unsigned short* xb = xs + (size_t)sl * NN * SLW + c;
        #pragma unroll
        for (int m = 0; m < 2; ++m) {
            int rbase = blockRow + m * 16 + (lg << 2);
            f32x4 a = acc[m][n];
            #pragma unroll
            for (int r = 0; r < 4; ++r) {
                int row = rbase + r;
                if (row < NN) {
                    float vv = fmaxf(a[r] + bv[n], 0.0f);
                    xb[(size_t)row * SLW] = (unsigned short)f2bf(vv);
                }
            }
        }
    }
}

// ---------------------------------------------------------------------------
// Kernel 2: out[i, s*32..s*32+32) = mean_k xs[s][edge[i,k], :].
// Persistent grid 2048 = 256 CU x 8; slice s = blockIdx.x & 7 pinned per XCD
// (3.2 MB slice L2-resident). Wave = 16 nodes; lane = node(g) x quad(q).
// Coalesced CACHED int4 edge load + static __shfl distribution.
// NT only on the write-once out stores.
// ---------------------------------------------------------------------------
__global__ __launch_bounds__(256) void gather_mean(
    const int* __restrict__ edge, const unsigned short* __restrict__ xs,
    float* __restrict__ out)
{
    const int s    = blockIdx.x & 7;
    const int lane = threadIdx.x & 63;
    const int w    = threadIdx.x >> 6;
    const int g    = lane >> 2, q = lane & 3;
    const unsigned short* xsl = xs + (size_t)s * NN * SLW;
    const unsigned qo = q * 8;

    for (int grp = blockIdx.x >> 3; grp < NGRP; grp += 256) {
        const int iw0 = grp * 64 + w * 16;
        const int i   = iw0 + g;

        int eoff = iw0 * KNB + lane * 4;
        if (eoff > NN * KNB - 4) eoff = NN * KNB - 4;
        i32x4 e4 = *(const i32x4*)(edge + eoff);
        int e[4] = { e4[0], e4[1], e4[2], e4[3] };

        float a[8];
        #pragma unroll
        for (int j = 0; j < 8; ++j) a[j] = 0.0f;

        #pragma unroll
        for (int k = 0; k < KNB; ++k) {
            int src = (lane & 60) | (k >> 2);       // lane holding e[node g][k]
            unsigned n = (unsigned)__shfl(e[k & 3], src, 64);
            bf16x8 v = *(const bf16x8*)(xsl + n * SLW + qo);
            const unsigned int* vu = (const unsigned int*)&v;
            #pragma unroll
            for (int j = 0; j < 4; ++j) {
                a[2 * j]     += bf2f(vu[j] & 0xffffu);
                a[2 * j + 1] += bf2f_hi(vu[j]);
            }
        }

        if (i < NN) {
            f32x4 o0 = { a[0] * 0.0625f, a[1] * 0.0625f, a[2] * 0.0625f, a[3] * 0.0625f };
            f32x4 o1 = { a[4] * 0.0625f, a[5] * 0.0625f, a[6] * 0.0625f, a[7] * 0.0625f };
            float* op = out + (size_t)i * DD + s * SLW + q * 8;
            __builtin_nontemporal_store(o0, (f32x4*)op);
            __builtin_nontemporal_store(o1, (f32x4*)(op + 4));
        }
    }
}

extern "C" void kernel_launch(void* const* d_in, const int* in_sizes, int n_in,
                              void* d_out, int out_size, void* d_ws, size_t ws_size,
                              hipStream_t stream) {
    // inputs: 0:idx 1:feats 2:edge_dict 3:sadj 4:epoch 5:W 6:b
    const float* feats = (const float*)d_in[1];
    const int*   edge  = (const int*)d_in[2];
    const float* W     = (const float*)d_in[5];
    const float* b     = (const float*)d_in[6];
    float* out = (float*)d_out;

    unsigned short* xs  = (unsigned short*)d_ws;                            // 25.6 MB sliced
    unsigned short* Wbf = (unsigned short*)((char*)d_ws + (size_t)NN * DD * 2); // +128 KB

    convert_w<<<dim3(32), dim3(256), 0, stream>>>(W, Wbf);
    gemm_relu<<<dim3(NB32), dim3(256), 0, stream>>>(feats, Wbf, b, xs);
    gather_mean<<<dim3(2048), dim3(256), 0, stream>>>(edge, xs, out);
}

// Round 11
// 65.253 us; speedup vs baseline: 1.5521x; 1.0505x over previous
//
#include <hip/hip_runtime.h>
#include <hip/hip_bf16.h>

#define NN  50000
#define DD  256
#define KNB 16
#define BM  32
#define NSL 8      // column slices (one per XCD)
#define SLW 32     // slice width in columns (64B bf16 rows -> line-pure slices)
#define NKT 8      // 256 / 32
#define NGRP ((NN + 63) / 64)    // 782 node-groups of 64 (gather)
#define NB32 ((NN + 31) / 32)    // 1563 row-blocks of 32 (gemm)

typedef __attribute__((ext_vector_type(8))) short bf16x8;
typedef __attribute__((ext_vector_type(4))) float f32x4;
typedef __attribute__((ext_vector_type(4))) int   i32x4;

static __device__ __forceinline__ float bf2f(unsigned int u16) {
    union { unsigned int i; float f; } c; c.i = u16 << 16; return c.f;
}
static __device__ __forceinline__ float bf2f_hi(unsigned int u) {
    union { unsigned int i; float f; } c; c.i = u & 0xffff0000u; return c.f;
}
static __device__ __forceinline__ short f2bf(float f) {
    union { float f; unsigned int i; } c; c.f = f;
    unsigned int r = c.i + 0x7FFFu + ((c.i >> 16) & 1u);   // RNE
    return (short)(r >> 16);
}
static __device__ __forceinline__ bf16x8 pack8(float4 a, float4 b) {
    union { __hip_bfloat162 h[4]; bf16x8 v; } u;
    u.h[0] = __float22bfloat162_rn(make_float2(a.x, a.y));
    u.h[1] = __float22bfloat162_rn(make_float2(a.z, a.w));
    u.h[2] = __float22bfloat162_rn(make_float2(b.x, b.y));
    u.h[3] = __float22bfloat162_rn(make_float2(b.z, b.w));
    return u.v;
}

#define GLOAD_LDS16(g, l) \
    __builtin_amdgcn_global_load_lds((const __attribute__((address_space(1))) unsigned int*)(g), \
                                     (__attribute__((address_space(3))) unsigned int*)(l), 16, 0, 0)

// ---------------------------------------------------------------------------
// Kernel 0: W (f32, row-major 256x256) -> bf16 fragment-tiled Wbf.
// slot s = ((kt*16 + nb)*4 + kb)*16 + j  holds 8 bf16:
//   Wbf[s*8 + e] = W[nb*16 + j][kt*32 + kb*8 + e]
// Per-kt tile = contiguous 16 KB, staged by global_load_lds in the GEMM.
// ---------------------------------------------------------------------------
__global__ void convert_w(const float* __restrict__ W, unsigned short* __restrict__ Wbf)
{
    int s = blockIdx.x * blockDim.x + threadIdx.x;   // 8192 slots
    if (s >= 8192) return;
    int j  = s & 15;
    int kb = (s >> 4) & 3;
    int nb = (s >> 6) & 15;
    int kt = s >> 10;
    const float4* p = (const float4*)(W + (nb * 16 + j) * DD + kt * 32 + kb * 8);
    *(bf16x8*)&Wbf[(size_t)s * 8] = pack8(p[0], p[1]);
}

// ---------------------------------------------------------------------------
// Kernel 1: x = relu(feats @ W^T + b) -> bf16 in SLICED layout:
//   xs[(col>>5)*NN*32 + row*32 + (col&31)]
// BM=32, 512 thr / 8 waves; wave wc owns cols [wc*32, wc*32+32) = slice wc.
// A (32x256, 16 KB) staged ONCE in prologue; W double-buffered 2x16 KB via
// global_load_lds from L2-resident pre-tiled Wbf, one barrier per K-step.
// LDS 48 KB, launch_bounds(512,6) -> 3 blocks/CU = 24 waves/CU (r10 had 12:
// not enough TLP to hide the per-step W drain -- gemm stuck at ~26 us).
// ---------------------------------------------------------------------------
__global__ __launch_bounds__(512, 6) void gemm_relu(
    const float* __restrict__ feats, const unsigned short* __restrict__ Wbf,
    const float* __restrict__ bias, unsigned short* __restrict__ xs)
{
    __shared__ short At[8192];         // 16 KB  [kt8][m2][kq4][i16][e8]
    __shared__ short Wt[2][8192];      // 32 KB  [nb16][kq4][j16][e8] per buf

    const int tid  = threadIdx.x;
    const int lane = tid & 63;
    const int wc   = tid >> 6;         // 0..7: wave = 32 rows x 32 cols
    const int l15  = lane & 15;
    const int lg   = lane >> 4;
    const int blockRow = blockIdx.x * BM;

    auto wstage = [&](int kt, int buf) {
        const char* src = (const char*)Wbf + kt * 16384 + tid * 16;
        char* dst = (char*)&Wt[buf][0] + tid * 16;
        GLOAD_LDS16(src, dst);
        GLOAD_LDS16(src + 8192, dst + 8192);
    };

    // ---- stage W(kt=0), then the whole 32x256 A tile (once) ----
    wstage(0, 0);
    {
        const int r = tid >> 4, c16 = tid & 15;   // row 0..31, 16-col chunk
        int row = blockRow + r; if (row > NN - 1) row = NN - 1;  // clamp; masked at store
        const float* base = feats + (size_t)row * DD + c16 * 16;
        const int m = r >> 4, i15 = r & 15;
        const int kt = c16 >> 1, kq0 = (c16 & 1) * 2;
        float4 a0 = *(const float4*)(base);
        float4 a1 = *(const float4*)(base + 4);
        float4 a2 = *(const float4*)(base + 8);
        float4 a3 = *(const float4*)(base + 12);
        int s0 = (((kt * 2 + m) * 4 + kq0) * 16 + i15) * 8;
        int s1 = (((kt * 2 + m) * 4 + kq0 + 1) * 16 + i15) * 8;
        *(bf16x8*)&At[s0] = pack8(a0, a1);
        *(bf16x8*)&At[s1] = pack8(a2, a3);
    }

    float bv[2];
    #pragma unroll
    for (int n = 0; n < 2; ++n) bv[n] = bias[wc * 32 + n * 16 + l15];

    f32x4 acc[2][2];
    #pragma unroll
    for (int m = 0; m < 2; ++m)
        #pragma unroll
        for (int n = 0; n < 2; ++n) acc[m][n] = (f32x4)0.0f;

    __syncthreads();   // A + W(0) ready

    #pragma unroll
    for (int kt = 0; kt < NKT; ++kt) {
        const int cur = kt & 1;
        if (kt + 1 < NKT) wstage(kt + 1, cur ^ 1);   // prefetch next W tile

        bf16x8 afr[2], bfr[2];
        #pragma unroll
        for (int m = 0; m < 2; ++m)
            afr[m] = *(const bf16x8*)&At[(((kt * 2 + m) * 4 + lg) * 16 + l15) * 8];
        #pragma unroll
        for (int n = 0; n < 2; ++n)
            bfr[n] = *(const bf16x8*)&Wt[cur][(((wc * 2 + n) * 4 + lg) * 16 + l15) * 8];

        #pragma unroll
        for (int m = 0; m < 2; ++m)
            #pragma unroll
            for (int n = 0; n < 2; ++n)
                acc[m][n] = __builtin_amdgcn_mfma_f32_16x16x32_bf16(
                    afr[m], bfr[n], acc[m][n], 0, 0, 0);

        __syncthreads();   // drains wstage(kt+1); Wt[cur^1] ready for next step
    }

    // ---- epilogue: bias + relu -> sliced bf16 store (wave wc = slice wc) ----
    unsigned short* xb = xs + (size_t)wc * NN * SLW;
    #pragma unroll
    for (int n = 0; n < 2; ++n) {
        const int c = n * 16 + l15;
        #pragma unroll
        for (int m = 0; m < 2; ++m) {
            int rbase = blockRow + m * 16 + (lg << 2);
            f32x4 a = acc[m][n];
            #pragma unroll
            for (int r = 0; r < 4; ++r) {
                int row = rbase + r;
                if (row < NN) {
                    float vv = fmaxf(a[r] + bv[n], 0.0f);
                    xb[(size_t)row * SLW + c] = (unsigned short)f2bf(vv);
                }
            }
        }
    }
}

// ---------------------------------------------------------------------------
// Kernel 2: out[i, s*32..s*32+32) = mean_k xs[s][edge[i,k], :].
// NON-persistent: 6256 blocks (one 64-node group x one slice each) -- the
// r10 persistent grid measured +10us vs this shape. Slice s = blockIdx.x & 7
// pinned per XCD (3.2 MB slice L2-resident). Wave = 16 nodes; lane =
// node(g) x quad(q). Coalesced CACHED int4 edge load + static __shfl.
// Gather loads batched 8-deep into registers (r10 VGPR=52 -> ~3 loads in
// flight, L2-latency-bound; batching -> ~8). NT only on out stores.
// ---------------------------------------------------------------------------
__global__ __launch_bounds__(256) void gather_mean(
    const int* __restrict__ edge, const unsigned short* __restrict__ xs,
    float* __restrict__ out)
{
    const int s    = blockIdx.x & 7;
    const int grp  = blockIdx.x >> 3;
    const int lane = threadIdx.x & 63;
    const int w    = threadIdx.x >> 6;
    const int g    = lane >> 2, q = lane & 3;
    const int iw0  = grp * 64 + w * 16;
    const int i    = iw0 + g;

    int eoff = iw0 * KNB + lane * 4;
    if (eoff > NN * KNB - 4) eoff = NN * KNB - 4;
    i32x4 e4 = *(const i32x4*)(edge + eoff);
    int e[4] = { e4[0], e4[1], e4[2], e4[3] };

    const unsigned short* xsl = xs + (size_t)s * NN * SLW;
    const unsigned qo = q * 8;

    float a[8];
    #pragma unroll
    for (int j = 0; j < 8; ++j) a[j] = 0.0f;

    #pragma unroll
    for (int half = 0; half < 2; ++half) {
        bf16x8 vbuf[8];
        #pragma unroll
        for (int kk = 0; kk < 8; ++kk) {            // issue 8 independent loads
            int k = half * 8 + kk;
            int src = (lane & 60) | (k >> 2);       // lane holding e[node g][k]
            unsigned n = (unsigned)__shfl(e[k & 3], src, 64);
            vbuf[kk] = *(const bf16x8*)(xsl + n * SLW + qo);
        }
        #pragma unroll
        for (int kk = 0; kk < 8; ++kk) {            // then consume
            const unsigned int* vu = (const unsigned int*)&vbuf[kk];
            #pragma unroll
            for (int j = 0; j < 4; ++j) {
                a[2 * j]     += bf2f(vu[j] & 0xffffu);
                a[2 * j + 1] += bf2f_hi(vu[j]);
            }
        }
    }

    if (i < NN) {
        f32x4 o0 = { a[0] * 0.0625f, a[1] * 0.0625f, a[2] * 0.0625f, a[3] * 0.0625f };
        f32x4 o1 = { a[4] * 0.0625f, a[5] * 0.0625f, a[6] * 0.0625f, a[7] * 0.0625f };
        float* op = out + (size_t)i * DD + s * SLW + q * 8;
        __builtin_nontemporal_store(o0, (f32x4*)op);
        __builtin_nontemporal_store(o1, (f32x4*)(op + 4));
    }
}

extern "C" void kernel_launch(void* const* d_in, const int* in_sizes, int n_in,
                              void* d_out, int out_size, void* d_ws, size_t ws_size,
                              hipStream_t stream) {
    // inputs: 0:idx 1:feats 2:edge_dict 3:sadj 4:epoch 5:W 6:b
    const float* feats = (const float*)d_in[1];
    const int*   edge  = (const int*)d_in[2];
    const float* W     = (const float*)d_in[5];
    const float* b     = (const float*)d_in[6];
    float* out = (float*)d_out;

    unsigned short* xs  = (unsigned short*)d_ws;                            // 25.6 MB sliced
    unsigned short* Wbf = (unsigned short*)((char*)d_ws + (size_t)NN * DD * 2); // +128 KB

    convert_w<<<dim3(32), dim3(256), 0, stream>>>(W, Wbf);
    gemm_relu<<<dim3(NB32), dim3(512), 0, stream>>>(feats, Wbf, b, xs);
    gather_mean<<<dim3(NGRP * NSL), dim3(256), 0, stream>>>(edge, xs, out);
}